// Round 1
// baseline (5724.218 us; speedup 1.0000x reference)
//
#include <hip/hip_runtime.h>
#include <cfloat>
#include <cstddef>

#define NODES 50000
#define EDGES 800000
#define HEADS 4
#define FEAT  64
#define HF    256   // HEADS*FEAT
#define NEG_SLOPE 0.2f

// ---- monotone float<->uint encoding for atomicMax on floats ----
__device__ __forceinline__ unsigned enc_f(float f) {
  unsigned u = __float_as_uint(f);
  return (u & 0x80000000u) ? ~u : (u | 0x80000000u);
}
__device__ __forceinline__ float dec_f(unsigned u) {
  return (u & 0x80000000u) ? __uint_as_float(u ^ 0x80000000u) : __uint_as_float(~u);
}

// ---- init emax/denom every call (harness poisons ws with 0xAA) ----
__global__ void init_kernel(unsigned* __restrict__ emax, float* __restrict__ denom) {
  int i = blockIdx.x * blockDim.x + threadIdx.x;
  if (i < NODES * HEADS) {
    emax[i] = enc_f(-FLT_MAX);
    denom[i] = 0.f;
  }
}

// ---- fused projection GEMM + per-head attention logits ----
// block = 256 threads = 4 waves; wave w handles head w (lane = feature f).
// Each thread owns one W column (64 regs); x rows staged in LDS, broadcast-read.
template<int ROWS>
__global__ __launch_bounds__(256) void proj_kernel(
    const float* __restrict__ x, const float* __restrict__ W,
    const float* __restrict__ al, const float* __restrict__ ar,
    float* __restrict__ h, float* __restrict__ el, float* __restrict__ er) {
  __shared__ float xs[ROWS * FEAT];
  const int c = threadIdx.x;          // output column 0..255
  const int head = c >> 6, f = c & 63;

  float Wc[FEAT];
#pragma unroll
  for (int k = 0; k < FEAT; ++k) Wc[k] = W[k * HF + c];
  const float alv = al[head * FEAT + f];
  const float arv = ar[head * FEAT + f];

  const int row0 = blockIdx.x * ROWS;
  for (int i = c; i < ROWS * FEAT; i += 256) {
    int r = row0 + (i >> 6);
    xs[i] = (r < NODES) ? x[r * FEAT + (i & 63)] : 0.f;
  }
  __syncthreads();

  for (int r = 0; r < ROWS; ++r) {
    const int row = row0 + r;
    if (row >= NODES) break;
    const float4* xr = (const float4*)&xs[r * FEAT];
    float v = 0.f;
#pragma unroll
    for (int k4 = 0; k4 < 16; ++k4) {
      float4 xv = xr[k4];
      v += xv.x * Wc[4 * k4 + 0] + xv.y * Wc[4 * k4 + 1] +
           xv.z * Wc[4 * k4 + 2] + xv.w * Wc[4 * k4 + 3];
    }
    h[(size_t)row * HF + c] = v;
    float sl = v * alv, sr = v * arv;
#pragma unroll
    for (int m = 32; m; m >>= 1) {
      sl += __shfl_xor(sl, m, 64);
      sr += __shfl_xor(sr, m, 64);
    }
    if (f == 0) {
      el[row * HEADS + head] = sl;
      er[row * HEADS + head] = sr;
    }
  }
}

__device__ __forceinline__ float edge_score(const float* el, const float* er,
                                            int s, int d, int hh) {
  float sc = el[s * HEADS + hh] + er[d * HEADS + hh];
  return sc > 0.f ? sc : NEG_SLOPE * sc;
}

// ---- pass 1: segment max over dst ----
__global__ void score_max_kernel(const int* __restrict__ src, const int* __restrict__ dst,
                                 const float* __restrict__ el, const float* __restrict__ er,
                                 unsigned* __restrict__ emax) {
  int i = blockIdx.x * blockDim.x + threadIdx.x;
  if (i >= EDGES * HEADS) return;
  int e = i >> 2, hh = i & 3;
  int s = src[e], d = dst[e];
  float sc = edge_score(el, er, s, d, hh);
  atomicMax(&emax[d * HEADS + hh], enc_f(sc));
}

// ---- pass 2: segment sum of exp(score - max) ----
__global__ void exp_sum_kernel(const int* __restrict__ src, const int* __restrict__ dst,
                               const float* __restrict__ el, const float* __restrict__ er,
                               const unsigned* __restrict__ emax, float* __restrict__ denom) {
  int i = blockIdx.x * blockDim.x + threadIdx.x;
  if (i >= EDGES * HEADS) return;
  int e = i >> 2, hh = i & 3;
  int s = src[e], d = dst[e];
  float sc = edge_score(el, er, s, d, hh);
  float m = dec_f(emax[d * HEADS + hh]);
  atomicAdd(&denom[d * HEADS + hh], expf(sc - m));
}

// ---- pass 3: weighted aggregation. One wave per edge; lane = hh*16 + fq,
// each lane moves a float4 of the head's 64 features. ----
__global__ __launch_bounds__(256) void aggregate_kernel(
    const int* __restrict__ src, const int* __restrict__ dst,
    const float* __restrict__ el, const float* __restrict__ er,
    const unsigned* __restrict__ emax, const float* __restrict__ denom,
    const float* __restrict__ h, float* __restrict__ out) {
  int gtid = blockIdx.x * blockDim.x + threadIdx.x;
  int e = gtid >> 6;
  if (e >= EDGES) return;
  int lane = threadIdx.x & 63;
  int hh = lane >> 4, fq = lane & 15;
  int s = __builtin_amdgcn_readfirstlane(src[e]);
  int d = __builtin_amdgcn_readfirstlane(dst[e]);
  float sc = edge_score(el, er, s, d, hh);
  float alpha = expf(sc - dec_f(emax[d * HEADS + hh])) / denom[d * HEADS + hh];
  const float4 hv = *(const float4*)&h[(size_t)s * HF + hh * FEAT + fq * 4];
  float* op = &out[(size_t)d * HF + hh * FEAT + fq * 4];
  atomicAdd(op + 0, hv.x * alpha);
  atomicAdd(op + 1, hv.y * alpha);
  atomicAdd(op + 2, hv.z * alpha);
  atomicAdd(op + 3, hv.w * alpha);
}

// ---- bias + (optional tanh) + head-mean ----
__global__ void act_mean_kernel(const float* __restrict__ agg, const float* __restrict__ b,
                                float* __restrict__ xout, int do_tanh) {
  int i = blockIdx.x * blockDim.x + threadIdx.x;  // n*FEAT + f
  if (i >= NODES * FEAT) return;
  int n = i >> 6, f = i & 63;
  float acc = 0.f;
#pragma unroll
  for (int hh = 0; hh < HEADS; ++hh) {
    float v = agg[(size_t)n * HF + hh * FEAT + f] + b[hh * FEAT + f];
    acc += do_tanh ? tanhf(v) : v;
  }
  xout[i] = acc * 0.25f;
}

extern "C" void kernel_launch(void* const* d_in, const int* in_sizes, int n_in,
                              void* d_out, int out_size, void* d_ws, size_t ws_size,
                              hipStream_t stream) {
  const float* x   = (const float*)d_in[0];
  const int*   src = (const int*)d_in[1];
  const int*   dst = (const int*)d_in[2];
  const float* Ws[2]  = {(const float*)d_in[3], (const float*)d_in[7]};
  const float* als[2] = {(const float*)d_in[4], (const float*)d_in[8]};
  const float* ars[2] = {(const float*)d_in[5], (const float*)d_in[9]};
  const float* bs[2]  = {(const float*)d_in[6], (const float*)d_in[10]};

  float* ws = (float*)d_ws;
  const size_t NHF = (size_t)NODES * HF;       // 12,800,000
  const size_t NF  = (size_t)NODES * FEAT;     //  3,200,000
  const size_t NH  = (size_t)NODES * HEADS;    //    200,000
  float*    hbuf  = ws;
  float*    agg   = ws + NHF;
  float*    x2    = ws + 2 * NHF;
  float*    el    = ws + 2 * NHF + NF;
  float*    er    = el + NH;
  unsigned* emax  = (unsigned*)(er + NH);
  float*    denom = (float*)(emax + NH);
  float*    outp  = (float*)d_out;

  const int ROWS = 32;
  const int proj_grid = (NODES + ROWS - 1) / ROWS;
  const int eh_grid   = (EDGES * HEADS + 255) / 256;
  const int agg_grid  = (EDGES * 64) / 256;
  const int nf_grid   = (NODES * FEAT + 255) / 256;
  const int nh_grid   = (NODES * HEADS + 255) / 256;

  for (int layer = 0; layer < 2; ++layer) {
    const float* in = (layer == 0) ? x : x2;
    hipMemsetAsync(agg, 0, NHF * sizeof(float), stream);
    init_kernel<<<nh_grid, 256, 0, stream>>>(emax, denom);
    proj_kernel<32><<<proj_grid, 256, 0, stream>>>(in, Ws[layer], als[layer], ars[layer],
                                                   hbuf, el, er);
    score_max_kernel<<<eh_grid, 256, 0, stream>>>(src, dst, el, er, emax);
    exp_sum_kernel<<<eh_grid, 256, 0, stream>>>(src, dst, el, er, emax, denom);
    aggregate_kernel<<<agg_grid, 256, 0, stream>>>(src, dst, el, er, emax, denom, hbuf, agg);
    act_mean_kernel<<<nf_grid, 256, 0, stream>>>(agg, bs[layer],
                                                 (layer == 0) ? x2 : outp, layer == 0);
  }
}

// Round 5
// 549.014 us; speedup vs baseline: 10.4264x; 10.4264x over previous
//
#include <hip/hip_runtime.h>
#include <cfloat>
#include <cstddef>

#define NODES 50000
#define EDGES 800000
#define HEADS 4
#define FEAT  64
#define HF    256   // HEADS*FEAT
#define NEG_SLOPE 0.2f

// ============ CSR build (per call; graph identical both layers) ============

__global__ void zero_deg_kernel(int* __restrict__ deg) {
  int i = blockIdx.x * blockDim.x + threadIdx.x;
  if (i < NODES) deg[i] = 0;
}

__global__ void count_deg_kernel(const int* __restrict__ dst, int* __restrict__ deg) {
  int e = blockIdx.x * blockDim.x + threadIdx.x;
  if (e < EDGES) atomicAdd(&deg[dst[e]], 1);
}

// Single-block scan, thread-coarsened x4: 50000 elems in 13 chunks of 4096.
__global__ __launch_bounds__(1024) void scan_kernel(const int* __restrict__ deg,
                                                    int* __restrict__ rowstart,
                                                    int* __restrict__ cursor) {
  __shared__ int wtot[16], wexcl[16];
  __shared__ int carry_s;
  const int tid = threadIdx.x, lane = tid & 63, wv = tid >> 6;
  if (tid == 0) carry_s = 0;
  __syncthreads();
  for (int base = 0; base < NODES; base += 4096) {
    const int i0 = base + tid * 4;
    int v0 = (i0 + 0 < NODES) ? deg[i0 + 0] : 0;
    int v1 = (i0 + 1 < NODES) ? deg[i0 + 1] : 0;
    int v2 = (i0 + 2 < NODES) ? deg[i0 + 2] : 0;
    int v3 = (i0 + 3 < NODES) ? deg[i0 + 3] : 0;
    const int t = v0 + v1 + v2 + v3;
    int x = t;
#pragma unroll
    for (int off = 1; off < 64; off <<= 1) {
      int u = __shfl_up(x, off, 64);
      if (lane >= off) x += u;
    }
    if (lane == 63) wtot[wv] = x;
    __syncthreads();
    if (wv == 0) {
      int wval = (lane < 16) ? wtot[lane] : 0;
      int wx = wval;
#pragma unroll
      for (int off = 1; off < 16; off <<= 1) {
        int u = __shfl_up(wx, off, 64);
        if (lane >= off) wx += u;
      }
      if (lane < 16) wexcl[lane] = wx - wval;
    }
    __syncthreads();
    const int carry = carry_s;
    int e = carry + wexcl[wv] + (x - t);   // exclusive prefix for this thread's 4
    if (i0 + 0 < NODES) { rowstart[i0 + 0] = e; cursor[i0 + 0] = e; } e += v0;
    if (i0 + 1 < NODES) { rowstart[i0 + 1] = e; cursor[i0 + 1] = e; } e += v1;
    if (i0 + 2 < NODES) { rowstart[i0 + 2] = e; cursor[i0 + 2] = e; } e += v2;
    if (i0 + 3 < NODES) { rowstart[i0 + 3] = e; cursor[i0 + 3] = e; }
    __syncthreads();                       // everyone has read carry_s
    if (tid == 1023) carry_s = carry + wexcl[15] + wtot[15];
    __syncthreads();
  }
}

__global__ void scatter_kernel(const int* __restrict__ src, const int* __restrict__ dst,
                               int* __restrict__ cursor, int* __restrict__ csr_src) {
  int e = blockIdx.x * blockDim.x + threadIdx.x;
  if (e < EDGES) {
    int pos = atomicAdd(&cursor[dst[e]], 1);
    csr_src[pos] = src[e];
  }
}

// ============ fused projection GEMM + attention logits ============
// block = 256 threads; thread owns one output column (64 W regs); x rows in LDS.
template<int ROWS>
__global__ __launch_bounds__(256) void proj_kernel(
    const float* __restrict__ x, const float* __restrict__ W,
    const float* __restrict__ al, const float* __restrict__ ar,
    float* __restrict__ h, float* __restrict__ el, float* __restrict__ er) {
  __shared__ float xs[ROWS * FEAT];
  const int c = threadIdx.x;          // output column 0..255
  const int head = c >> 6, f = c & 63;

  float Wc[FEAT];
#pragma unroll
  for (int k = 0; k < FEAT; ++k) Wc[k] = W[k * HF + c];
  const float alv = al[head * FEAT + f];
  const float arv = ar[head * FEAT + f];

  const int row0 = blockIdx.x * ROWS;
  for (int i = c; i < ROWS * FEAT; i += 256) {
    int r = row0 + (i >> 6);
    xs[i] = (r < NODES) ? x[r * FEAT + (i & 63)] : 0.f;
  }
  __syncthreads();

  for (int r = 0; r < ROWS; ++r) {
    const int row = row0 + r;
    if (row >= NODES) break;
    const float4* xr = (const float4*)&xs[r * FEAT];
    float v = 0.f;
#pragma unroll
    for (int k4 = 0; k4 < 16; ++k4) {
      float4 xv = xr[k4];
      v += xv.x * Wc[4 * k4 + 0] + xv.y * Wc[4 * k4 + 1] +
           xv.z * Wc[4 * k4 + 2] + xv.w * Wc[4 * k4 + 3];
    }
    h[(size_t)row * HF + c] = v;
    float sl = v * alv, sr = v * arv;
#pragma unroll
    for (int m = 32; m; m >>= 1) {
      sl += __shfl_xor(sl, m, 64);
      sr += __shfl_xor(sr, m, 64);
    }
    if (f == 0) {
      el[row * HEADS + head] = sl;   // layout [n][4] -> float4 addressable
      er[row * HEADS + head] = sr;
    }
  }
}

// ============ fused per-node: segment softmax + aggregation + bias/act/mean ====
// One wave per dst node. lane = hh*16 + fq; lane moves float4 of head hh's feats.
__device__ __forceinline__ float lrelu(float s) { return s > 0.f ? s : NEG_SLOPE * s; }

template<int DO_TANH>
__global__ __launch_bounds__(256) void node_kernel(
    const int* __restrict__ rowstart, const int* __restrict__ deg,
    const int* __restrict__ csr_src,
    const float* __restrict__ el, const float* __restrict__ er,
    const float* __restrict__ h, const float* __restrict__ bias,
    float* __restrict__ out) {
  const int node = (blockIdx.x * blockDim.x + threadIdx.x) >> 6;
  if (node >= NODES) return;
  const int lane = threadIdx.x & 63;
  const int hh = lane >> 4, fq = lane & 15;
  const int rs = rowstart[node];
  const int dg = deg[node];

  float4 acc = make_float4(0.f, 0.f, 0.f, 0.f);

  if (dg > 0) {
    const float4 erv = *(const float4*)&er[node * 4];
    // ---- pass A: per-head max over incoming edges (lanes parallel) ----
    float m0 = -FLT_MAX, m1 = -FLT_MAX, m2 = -FLT_MAX, m3 = -FLT_MAX;
    for (int i = lane; i < dg; i += 64) {
      int s = csr_src[rs + i];
      float4 ev = *(const float4*)&el[s * 4];
      m0 = fmaxf(m0, lrelu(ev.x + erv.x));
      m1 = fmaxf(m1, lrelu(ev.y + erv.y));
      m2 = fmaxf(m2, lrelu(ev.z + erv.z));
      m3 = fmaxf(m3, lrelu(ev.w + erv.w));
    }
#pragma unroll
    for (int off = 32; off; off >>= 1) {
      m0 = fmaxf(m0, __shfl_xor(m0, off, 64));
      m1 = fmaxf(m1, __shfl_xor(m1, off, 64));
      m2 = fmaxf(m2, __shfl_xor(m2, off, 64));
      m3 = fmaxf(m3, __shfl_xor(m3, off, 64));
    }
    // ---- pass B: per-head sum of exp ----
    float q0 = 0.f, q1 = 0.f, q2 = 0.f, q3 = 0.f;
    for (int i = lane; i < dg; i += 64) {
      int s = csr_src[rs + i];
      float4 ev = *(const float4*)&el[s * 4];
      q0 += __expf(lrelu(ev.x + erv.x) - m0);
      q1 += __expf(lrelu(ev.y + erv.y) - m1);
      q2 += __expf(lrelu(ev.z + erv.z) - m2);
      q3 += __expf(lrelu(ev.w + erv.w) - m3);
    }
#pragma unroll
    for (int off = 32; off; off >>= 1) {
      q0 += __shfl_xor(q0, off, 64);
      q1 += __shfl_xor(q1, off, 64);
      q2 += __shfl_xor(q2, off, 64);
      q3 += __shfl_xor(q3, off, 64);
    }
    const float r0 = 1.f / q0, r1 = 1.f / q1, r2 = 1.f / q2, r3 = 1.f / q3;
    // ---- pass C: aggregate, chunks of 64 edges ----
    for (int base = 0; base < dg; base += 64) {
      const int cnt = min(64, dg - base);
      int sL = 0;
      float A0 = 0.f, A1 = 0.f, A2 = 0.f, A3 = 0.f;
      if (base + lane < dg) {
        sL = csr_src[rs + base + lane];
        float4 ev = *(const float4*)&el[sL * 4];
        A0 = __expf(lrelu(ev.x + erv.x) - m0) * r0;
        A1 = __expf(lrelu(ev.y + erv.y) - m1) * r1;
        A2 = __expf(lrelu(ev.z + erv.z) - m2) * r2;
        A3 = __expf(lrelu(ev.w + erv.w) - m3) * r3;
      }
      for (int i = 0; i < cnt; ++i) {
        const int s = __shfl(sL, i, 64);
        const float a0 = __shfl(A0, i, 64);
        const float a1 = __shfl(A1, i, 64);
        const float a2 = __shfl(A2, i, 64);
        const float a3 = __shfl(A3, i, 64);
        const float av = (hh == 0) ? a0 : (hh == 1) ? a1 : (hh == 2) ? a2 : a3;
        const float4 hv = *(const float4*)&h[(size_t)s * HF + hh * FEAT + fq * 4];
        acc.x += hv.x * av;
        acc.y += hv.y * av;
        acc.z += hv.z * av;
        acc.w += hv.w * av;
      }
    }
  }

  // ---- bias + activation + head-mean (cross-head shfl reduce) ----
  const float4 bv = *(const float4*)&bias[hh * FEAT + fq * 4];
  float vx = acc.x + bv.x, vy = acc.y + bv.y, vz = acc.z + bv.z, vw = acc.w + bv.w;
  if (DO_TANH) { vx = tanhf(vx); vy = tanhf(vy); vz = tanhf(vz); vw = tanhf(vw); }
#pragma unroll
  for (int off = 16; off <= 32; off <<= 1) {
    vx += __shfl_xor(vx, off, 64);
    vy += __shfl_xor(vy, off, 64);
    vz += __shfl_xor(vz, off, 64);
    vw += __shfl_xor(vw, off, 64);
  }
  if (hh == 0) {
    *(float4*)&out[(size_t)node * FEAT + fq * 4] =
        make_float4(vx * 0.25f, vy * 0.25f, vz * 0.25f, vw * 0.25f);
  }
}

// ============ launch ============

extern "C" void kernel_launch(void* const* d_in, const int* in_sizes, int n_in,
                              void* d_out, int out_size, void* d_ws, size_t ws_size,
                              hipStream_t stream) {
  const float* x   = (const float*)d_in[0];
  const int*   src = (const int*)d_in[1];
  const int*   dst = (const int*)d_in[2];
  const float* Ws[2]  = {(const float*)d_in[3], (const float*)d_in[7]};
  const float* als[2] = {(const float*)d_in[4], (const float*)d_in[8]};
  const float* ars[2] = {(const float*)d_in[5], (const float*)d_in[9]};
  const float* bs[2]  = {(const float*)d_in[6], (const float*)d_in[10]};

  float* ws = (float*)d_ws;
  const size_t NHF = (size_t)NODES * HF;   // 12.8M
  const size_t NF  = (size_t)NODES * FEAT; // 3.2M
  const size_t NH  = (size_t)NODES * HEADS;// 200K
  float* hbuf = ws;
  float* x2   = ws + NHF;
  float* el   = ws + NHF + NF;
  float* er   = el + NH;
  int* ibase   = (int*)(er + NH);
  int* deg      = ibase;
  int* rowstart = ibase + NODES;
  int* cursor   = ibase + 2 * NODES;
  int* csr_src  = ibase + 3 * NODES;
  float* outp = (float*)d_out;

  const int ROWS = 32;
  const int proj_grid = (NODES + ROWS - 1) / ROWS;
  const int edge_grid = (EDGES + 255) / 256;
  const int node_grid = (NODES * 64) / 256;  // one wave per node
  const int n_grid    = (NODES + 255) / 256;

  // CSR build (once; both layers share the graph)
  zero_deg_kernel<<<n_grid, 256, 0, stream>>>(deg);
  count_deg_kernel<<<edge_grid, 256, 0, stream>>>(dst, deg);
  scan_kernel<<<1, 1024, 0, stream>>>(deg, rowstart, cursor);
  scatter_kernel<<<edge_grid, 256, 0, stream>>>(src, dst, cursor, csr_src);

  // Layer 1
  proj_kernel<ROWS><<<proj_grid, 256, 0, stream>>>(x, Ws[0], als[0], ars[0], hbuf, el, er);
  node_kernel<1><<<node_grid, 256, 0, stream>>>(rowstart, deg, csr_src, el, er,
                                                hbuf, bs[0], x2);
  // Layer 2
  proj_kernel<ROWS><<<proj_grid, 256, 0, stream>>>(x2, Ws[1], als[1], ars[1], hbuf, el, er);
  node_kernel<0><<<node_grid, 256, 0, stream>>>(rowstart, deg, csr_src, el, er,
                                                hbuf, bs[1], outp);
}

// Round 6
// 492.350 us; speedup vs baseline: 11.6263x; 1.1151x over previous
//
#include <hip/hip_runtime.h>
#include <hip/hip_fp16.h>
#include <cfloat>
#include <cstddef>

#define NODES 50000
#define EDGES 800000
#define HEADS 4
#define FEAT  64
#define HF    256   // HEADS*FEAT
#define NEG_SLOPE 0.2f

// ============ CSR build (per call; graph identical both layers) ============

__global__ void zero_deg_kernel(int* __restrict__ deg) {
  int i = blockIdx.x * blockDim.x + threadIdx.x;
  if (i < NODES) deg[i] = 0;
}

__global__ void count_deg_kernel(const int* __restrict__ dst, int* __restrict__ deg) {
  int e = blockIdx.x * blockDim.x + threadIdx.x;
  if (e < EDGES) atomicAdd(&deg[dst[e]], 1);
}

// Single-block scan, thread-coarsened x4: 50000 elems in 13 chunks of 4096.
__global__ __launch_bounds__(1024) void scan_kernel(const int* __restrict__ deg,
                                                    int* __restrict__ rowstart,
                                                    int* __restrict__ cursor) {
  __shared__ int wtot[16], wexcl[16];
  __shared__ int carry_s;
  const int tid = threadIdx.x, lane = tid & 63, wv = tid >> 6;
  if (tid == 0) carry_s = 0;
  __syncthreads();
  for (int base = 0; base < NODES; base += 4096) {
    const int i0 = base + tid * 4;
    int v0 = (i0 + 0 < NODES) ? deg[i0 + 0] : 0;
    int v1 = (i0 + 1 < NODES) ? deg[i0 + 1] : 0;
    int v2 = (i0 + 2 < NODES) ? deg[i0 + 2] : 0;
    int v3 = (i0 + 3 < NODES) ? deg[i0 + 3] : 0;
    const int t = v0 + v1 + v2 + v3;
    int x = t;
#pragma unroll
    for (int off = 1; off < 64; off <<= 1) {
      int u = __shfl_up(x, off, 64);
      if (lane >= off) x += u;
    }
    if (lane == 63) wtot[wv] = x;
    __syncthreads();
    if (wv == 0) {
      int wval = (lane < 16) ? wtot[lane] : 0;
      int wx = wval;
#pragma unroll
      for (int off = 1; off < 16; off <<= 1) {
        int u = __shfl_up(wx, off, 64);
        if (lane >= off) wx += u;
      }
      if (lane < 16) wexcl[lane] = wx - wval;
    }
    __syncthreads();
    const int carry = carry_s;
    int e = carry + wexcl[wv] + (x - t);   // exclusive prefix for this thread's 4
    if (i0 + 0 < NODES) { rowstart[i0 + 0] = e; cursor[i0 + 0] = e; } e += v0;
    if (i0 + 1 < NODES) { rowstart[i0 + 1] = e; cursor[i0 + 1] = e; } e += v1;
    if (i0 + 2 < NODES) { rowstart[i0 + 2] = e; cursor[i0 + 2] = e; } e += v2;
    if (i0 + 3 < NODES) { rowstart[i0 + 3] = e; cursor[i0 + 3] = e; }
    __syncthreads();                       // everyone has read carry_s
    if (tid == 1023) carry_s = carry + wexcl[15] + wtot[15];
    __syncthreads();
  }
}

__global__ void scatter_kernel(const int* __restrict__ src, const int* __restrict__ dst,
                               int* __restrict__ cursor, int* __restrict__ csr_src) {
  int e = blockIdx.x * blockDim.x + threadIdx.x;
  if (e < EDGES) {
    int pos = atomicAdd(&cursor[dst[e]], 1);
    csr_src[pos] = src[e];
  }
}

// ============ fused projection GEMM + attention logits ============
// block = 256 threads; thread owns one output column (64 W regs); x rows in LDS.
// h is written as fp16 (only the aggregated values are quantized; el/er stay fp32).
template<int ROWS>
__global__ __launch_bounds__(256) void proj_kernel(
    const float* __restrict__ x, const float* __restrict__ W,
    const float* __restrict__ al, const float* __restrict__ ar,
    __half* __restrict__ h, float* __restrict__ el, float* __restrict__ er) {
  __shared__ float xs[ROWS * FEAT];
  const int c = threadIdx.x;          // output column 0..255
  const int head = c >> 6, f = c & 63;

  float Wc[FEAT];
#pragma unroll
  for (int k = 0; k < FEAT; ++k) Wc[k] = W[k * HF + c];
  const float alv = al[head * FEAT + f];
  const float arv = ar[head * FEAT + f];

  const int row0 = blockIdx.x * ROWS;
  for (int i = c; i < ROWS * FEAT; i += 256) {
    int r = row0 + (i >> 6);
    xs[i] = (r < NODES) ? x[r * FEAT + (i & 63)] : 0.f;
  }
  __syncthreads();

  for (int r = 0; r < ROWS; ++r) {
    const int row = row0 + r;
    if (row >= NODES) break;
    const float4* xr = (const float4*)&xs[r * FEAT];
    float v = 0.f;
#pragma unroll
    for (int k4 = 0; k4 < 16; ++k4) {
      float4 xv = xr[k4];
      v += xv.x * Wc[4 * k4 + 0] + xv.y * Wc[4 * k4 + 1] +
           xv.z * Wc[4 * k4 + 2] + xv.w * Wc[4 * k4 + 3];
    }
    h[(size_t)row * HF + c] = __float2half(v);
    float sl = v * alv, sr = v * arv;
#pragma unroll
    for (int m = 32; m; m >>= 1) {
      sl += __shfl_xor(sl, m, 64);
      sr += __shfl_xor(sr, m, 64);
    }
    if (f == 0) {
      el[row * HEADS + head] = sl;   // layout [n][4] -> float4 addressable
      er[row * HEADS + head] = sr;
    }
  }
}

// ============ fused per-node: segment softmax + aggregation + bias/act/mean ====
// One wave per dst node. lane = hh*16 + fq; lane moves 4 fp16 feats (8B) per edge.
__device__ __forceinline__ float lrelu(float s) { return s > 0.f ? s : NEG_SLOPE * s; }

__device__ __forceinline__ void gather_fma(const __half* __restrict__ h, int s,
                                           int hh, int fq, float av, float4& acc) {
  union { uint2 u; __half2 h2[2]; } cvt;
  cvt.u = *(const uint2*)(h + (size_t)s * HF + hh * FEAT + fq * 4);
  float2 f01 = __half22float2(cvt.h2[0]);
  float2 f23 = __half22float2(cvt.h2[1]);
  acc.x += f01.x * av;
  acc.y += f01.y * av;
  acc.z += f23.x * av;
  acc.w += f23.y * av;
}

template<int DO_TANH>
__global__ __launch_bounds__(256) void node_kernel(
    const int* __restrict__ rowstart, const int* __restrict__ deg,
    const int* __restrict__ csr_src,
    const float* __restrict__ el, const float* __restrict__ er,
    const __half* __restrict__ h, const float* __restrict__ bias,
    float* __restrict__ out) {
  const int node = (blockIdx.x * blockDim.x + threadIdx.x) >> 6;
  if (node >= NODES) return;
  const int lane = threadIdx.x & 63;
  const int hh = lane >> 4, fq = lane & 15;
  const int rs = rowstart[node];
  const int dg = deg[node];

  float4 acc = make_float4(0.f, 0.f, 0.f, 0.f);

  if (dg > 0) {
    const float4 erv = *(const float4*)&er[node * 4];
    if (dg <= 64) {
      // ---- fast path: one edge per lane; scores/alpha computed once ----
      int sL = 0;
      float s0 = -FLT_MAX, s1 = -FLT_MAX, s2 = -FLT_MAX, s3 = -FLT_MAX;
      if (lane < dg) {
        sL = csr_src[rs + lane];
        float4 ev = *(const float4*)&el[sL * 4];
        s0 = lrelu(ev.x + erv.x);
        s1 = lrelu(ev.y + erv.y);
        s2 = lrelu(ev.z + erv.z);
        s3 = lrelu(ev.w + erv.w);
      }
      float m0 = s0, m1 = s1, m2 = s2, m3 = s3;
#pragma unroll
      for (int off = 32; off; off >>= 1) {
        m0 = fmaxf(m0, __shfl_xor(m0, off, 64));
        m1 = fmaxf(m1, __shfl_xor(m1, off, 64));
        m2 = fmaxf(m2, __shfl_xor(m2, off, 64));
        m3 = fmaxf(m3, __shfl_xor(m3, off, 64));
      }
      float E0 = 0.f, E1 = 0.f, E2 = 0.f, E3 = 0.f;
      if (lane < dg) {
        E0 = __expf(s0 - m0);
        E1 = __expf(s1 - m1);
        E2 = __expf(s2 - m2);
        E3 = __expf(s3 - m3);
      }
      float q0 = E0, q1 = E1, q2 = E2, q3 = E3;
#pragma unroll
      for (int off = 32; off; off >>= 1) {
        q0 += __shfl_xor(q0, off, 64);
        q1 += __shfl_xor(q1, off, 64);
        q2 += __shfl_xor(q2, off, 64);
        q3 += __shfl_xor(q3, off, 64);
      }
      const float A0 = E0 / q0, A1 = E1 / q1, A2 = E2 / q2, A3 = E3 / q3;
      for (int i = 0; i < dg; ++i) {
        const int s = __shfl(sL, i, 64);
        const float a0 = __shfl(A0, i, 64);
        const float a1 = __shfl(A1, i, 64);
        const float a2 = __shfl(A2, i, 64);
        const float a3 = __shfl(A3, i, 64);
        const float av = (hh == 0) ? a0 : (hh == 1) ? a1 : (hh == 2) ? a2 : a3;
        gather_fma(h, s, hh, fq, av, acc);
      }
    } else {
      // ---- general 3-pass path (deg > 64; rare) ----
      float m0 = -FLT_MAX, m1 = -FLT_MAX, m2 = -FLT_MAX, m3 = -FLT_MAX;
      for (int i = lane; i < dg; i += 64) {
        int s = csr_src[rs + i];
        float4 ev = *(const float4*)&el[s * 4];
        m0 = fmaxf(m0, lrelu(ev.x + erv.x));
        m1 = fmaxf(m1, lrelu(ev.y + erv.y));
        m2 = fmaxf(m2, lrelu(ev.z + erv.z));
        m3 = fmaxf(m3, lrelu(ev.w + erv.w));
      }
#pragma unroll
      for (int off = 32; off; off >>= 1) {
        m0 = fmaxf(m0, __shfl_xor(m0, off, 64));
        m1 = fmaxf(m1, __shfl_xor(m1, off, 64));
        m2 = fmaxf(m2, __shfl_xor(m2, off, 64));
        m3 = fmaxf(m3, __shfl_xor(m3, off, 64));
      }
      float q0 = 0.f, q1 = 0.f, q2 = 0.f, q3 = 0.f;
      for (int i = lane; i < dg; i += 64) {
        int s = csr_src[rs + i];
        float4 ev = *(const float4*)&el[s * 4];
        q0 += __expf(lrelu(ev.x + erv.x) - m0);
        q1 += __expf(lrelu(ev.y + erv.y) - m1);
        q2 += __expf(lrelu(ev.z + erv.z) - m2);
        q3 += __expf(lrelu(ev.w + erv.w) - m3);
      }
#pragma unroll
      for (int off = 32; off; off >>= 1) {
        q0 += __shfl_xor(q0, off, 64);
        q1 += __shfl_xor(q1, off, 64);
        q2 += __shfl_xor(q2, off, 64);
        q3 += __shfl_xor(q3, off, 64);
      }
      const float r0 = 1.f / q0, r1 = 1.f / q1, r2 = 1.f / q2, r3 = 1.f / q3;
      for (int base = 0; base < dg; base += 64) {
        const int cnt = min(64, dg - base);
        int sL = 0;
        float A0 = 0.f, A1 = 0.f, A2 = 0.f, A3 = 0.f;
        if (base + lane < dg) {
          sL = csr_src[rs + base + lane];
          float4 ev = *(const float4*)&el[sL * 4];
          A0 = __expf(lrelu(ev.x + erv.x) - m0) * r0;
          A1 = __expf(lrelu(ev.y + erv.y) - m1) * r1;
          A2 = __expf(lrelu(ev.z + erv.z) - m2) * r2;
          A3 = __expf(lrelu(ev.w + erv.w) - m3) * r3;
        }
        for (int i = 0; i < cnt; ++i) {
          const int s = __shfl(sL, i, 64);
          const float a0 = __shfl(A0, i, 64);
          const float a1 = __shfl(A1, i, 64);
          const float a2 = __shfl(A2, i, 64);
          const float a3 = __shfl(A3, i, 64);
          const float av = (hh == 0) ? a0 : (hh == 1) ? a1 : (hh == 2) ? a2 : a3;
          gather_fma(h, s, hh, fq, av, acc);
        }
      }
    }
  }

  // ---- bias + activation + head-mean (cross-head shfl reduce) ----
  const float4 bv = *(const float4*)&bias[hh * FEAT + fq * 4];
  float vx = acc.x + bv.x, vy = acc.y + bv.y, vz = acc.z + bv.z, vw = acc.w + bv.w;
  if (DO_TANH) { vx = tanhf(vx); vy = tanhf(vy); vz = tanhf(vz); vw = tanhf(vw); }
#pragma unroll
  for (int off = 16; off <= 32; off <<= 1) {
    vx += __shfl_xor(vx, off, 64);
    vy += __shfl_xor(vy, off, 64);
    vz += __shfl_xor(vz, off, 64);
    vw += __shfl_xor(vw, off, 64);
  }
  if (hh == 0) {
    *(float4*)&out[(size_t)node * FEAT + fq * 4] =
        make_float4(vx * 0.25f, vy * 0.25f, vz * 0.25f, vw * 0.25f);
  }
}

// ============ launch ============

extern "C" void kernel_launch(void* const* d_in, const int* in_sizes, int n_in,
                              void* d_out, int out_size, void* d_ws, size_t ws_size,
                              hipStream_t stream) {
  const float* x   = (const float*)d_in[0];
  const int*   src = (const int*)d_in[1];
  const int*   dst = (const int*)d_in[2];
  const float* Ws[2]  = {(const float*)d_in[3], (const float*)d_in[7]};
  const float* als[2] = {(const float*)d_in[4], (const float*)d_in[8]};
  const float* ars[2] = {(const float*)d_in[5], (const float*)d_in[9]};
  const float* bs[2]  = {(const float*)d_in[6], (const float*)d_in[10]};

  float* ws = (float*)d_ws;
  const size_t NHF = (size_t)NODES * HF;   // 12.8M elems
  const size_t NF  = (size_t)NODES * FEAT; // 3.2M
  const size_t NH  = (size_t)NODES * HEADS;// 200K
  __half* hbuf = (__half*)ws;              // NHF halves = NHF/2 float slots
  float* x2   = ws + NHF / 2;
  float* el   = x2 + NF;
  float* er   = el + NH;
  int* ibase   = (int*)(er + NH);
  int* deg      = ibase;
  int* rowstart = ibase + NODES;
  int* cursor   = ibase + 2 * NODES;
  int* csr_src  = ibase + 3 * NODES;
  float* outp = (float*)d_out;

  const int ROWS = 32;
  const int proj_grid = (NODES + ROWS - 1) / ROWS;
  const int edge_grid = (EDGES + 255) / 256;
  const int node_grid = (NODES * 64) / 256;  // one wave per node
  const int n_grid    = (NODES + 255) / 256;

  // CSR build (once; both layers share the graph)
  zero_deg_kernel<<<n_grid, 256, 0, stream>>>(deg);
  count_deg_kernel<<<edge_grid, 256, 0, stream>>>(dst, deg);
  scan_kernel<<<1, 1024, 0, stream>>>(deg, rowstart, cursor);
  scatter_kernel<<<edge_grid, 256, 0, stream>>>(src, dst, cursor, csr_src);

  // Layer 1
  proj_kernel<ROWS><<<proj_grid, 256, 0, stream>>>(x, Ws[0], als[0], ars[0], hbuf, el, er);
  node_kernel<1><<<node_grid, 256, 0, stream>>>(rowstart, deg, csr_src, el, er,
                                                hbuf, bs[0], x2);
  // Layer 2
  proj_kernel<ROWS><<<proj_grid, 256, 0, stream>>>(x2, Ws[1], als[1], ars[1], hbuf, el, er);
  node_kernel<0><<<node_grid, 256, 0, stream>>>(rowstart, deg, csr_src, el, er,
                                                hbuf, bs[1], outp);
}

// Round 8
// 464.355 us; speedup vs baseline: 12.3272x; 1.0603x over previous
//
#include <hip/hip_runtime.h>
#include <hip/hip_fp16.h>
#include <cfloat>
#include <cstddef>

#define NODES 50000
#define EDGES 800000
#define HEADS 4
#define FEAT  64
#define HF    256   // HEADS*FEAT
#define NEG_SLOPE 0.2f

#define ROWS 32
#define PROJ_BLOCKS ((NODES + ROWS - 1) / ROWS)   // 1563
#define COUNT_BLOCKS ((EDGES + 255) / 256)        // 3125

// ============ CSR build ============

__global__ void zero_deg_kernel(int* __restrict__ deg) {
  int i = blockIdx.x * blockDim.x + threadIdx.x;
  if (i < NODES) deg[i] = 0;
}

// LDS-staged single-block scan: 4 chunks of 13312, coalesced I/O, 13 elems/thread.
#define SCHUNK 13312
#define SPER   13
__global__ __launch_bounds__(1024) void scan_kernel(const int* __restrict__ deg,
                                                    int* __restrict__ rowstart,
                                                    int* __restrict__ cursor) {
  __shared__ int buf[SCHUNK];          // 52 KB
  __shared__ int wsum[16];
  __shared__ int carry_s;
  const int tid = threadIdx.x, lane = tid & 63, wv = tid >> 6;
  if (tid == 0) carry_s = 0;
  for (int base = 0; base < NODES; base += SCHUNK) {
    const int sz = min(SCHUNK, NODES - base);
    for (int i = tid; i < sz; i += 1024) buf[i] = deg[base + i];
    __syncthreads();
    const int o = tid * SPER;
    int tsum = 0;
#pragma unroll
    for (int j = 0; j < SPER; ++j) {
      int idx = o + j;
      if (idx < sz) tsum += buf[idx];
    }
    int x = tsum;
#pragma unroll
    for (int off = 1; off < 64; off <<= 1) {
      int u = __shfl_up(x, off, 64);
      if (lane >= off) x += u;
    }
    if (lane == 63) wsum[wv] = x;
    __syncthreads();
    if (wv == 0) {
      int wval = (lane < 16) ? wsum[lane] : 0;
      int wx = wval;
#pragma unroll
      for (int off = 1; off < 16; off <<= 1) {
        int u = __shfl_up(wx, off, 64);
        if (lane >= off) wx += u;
      }
      if (lane < 16) wsum[lane] = wx - wval;   // exclusive wave offsets
    }
    __syncthreads();
    const int carry = carry_s;
    int run = carry + wsum[wv] + (x - tsum);   // thread's exclusive prefix
#pragma unroll
    for (int j = 0; j < SPER; ++j) {
      int idx = o + j;
      if (idx < sz) { int t = buf[idx]; buf[idx] = run; run += t; }
    }
    __syncthreads();
    for (int i = tid; i < sz; i += 1024) {
      int v = buf[i];
      rowstart[base + i] = v;
      cursor[base + i] = v;
    }
    __syncthreads();
    if (tid == 1023) carry_s = run;            // = carry + chunk total
    __syncthreads();
  }
}

__global__ void scatter_kernel(const int* __restrict__ src, const int* __restrict__ dst,
                               int* __restrict__ cursor, int* __restrict__ csr_src) {
  int e = blockIdx.x * blockDim.x + threadIdx.x;
  if (e < EDGES) {
    int pos = atomicAdd(&cursor[dst[e]], 1);
    csr_src[pos] = src[e];
  }
}

// ============ fused projection GEMM + attention logits (+optional edge count) ====
// proj blocks: thread owns one output column (64 W regs); x rows in LDS.
// 4 interleaved accumulators break the serial FMA dependency chain.
__device__ __forceinline__ void proj_body(
    const float* __restrict__ x, const float* __restrict__ W,
    const float* __restrict__ al, const float* __restrict__ ar,
    __half* __restrict__ h, float* __restrict__ el, float* __restrict__ er,
    int blk) {
  __shared__ float xs[ROWS * FEAT];
  const int c = threadIdx.x;          // output column 0..255
  const int head = c >> 6, f = c & 63;

  float Wc[FEAT];
#pragma unroll
  for (int k = 0; k < FEAT; ++k) Wc[k] = W[k * HF + c];
  const float alv = al[head * FEAT + f];
  const float arv = ar[head * FEAT + f];

  const int row0 = blk * ROWS;
  for (int i = c; i < ROWS * FEAT; i += 256) {
    int r = row0 + (i >> 6);
    xs[i] = (r < NODES) ? x[r * FEAT + (i & 63)] : 0.f;
  }
  __syncthreads();

  for (int r = 0; r < ROWS; ++r) {
    const int row = row0 + r;
    if (row >= NODES) break;
    const float4* xr = (const float4*)&xs[r * FEAT];
    float vs0 = 0.f, vs1 = 0.f, vs2 = 0.f, vs3 = 0.f;
#pragma unroll
    for (int k4 = 0; k4 < 16; k4 += 4) {
      float4 a = xr[k4 + 0];
      float4 b = xr[k4 + 1];
      float4 cc = xr[k4 + 2];
      float4 d = xr[k4 + 3];
      vs0 += a.x * Wc[4 * k4 + 0] + a.y * Wc[4 * k4 + 1] +
             a.z * Wc[4 * k4 + 2] + a.w * Wc[4 * k4 + 3];
      vs1 += b.x * Wc[4 * k4 + 4] + b.y * Wc[4 * k4 + 5] +
             b.z * Wc[4 * k4 + 6] + b.w * Wc[4 * k4 + 7];
      vs2 += cc.x * Wc[4 * k4 + 8] + cc.y * Wc[4 * k4 + 9] +
             cc.z * Wc[4 * k4 + 10] + cc.w * Wc[4 * k4 + 11];
      vs3 += d.x * Wc[4 * k4 + 12] + d.y * Wc[4 * k4 + 13] +
             d.z * Wc[4 * k4 + 14] + d.w * Wc[4 * k4 + 15];
    }
    const float v = (vs0 + vs1) + (vs2 + vs3);
    h[(size_t)row * HF + c] = __float2half(v);
    float sl = v * alv, sr = v * arv;
#pragma unroll
    for (int m = 32; m; m >>= 1) {
      sl += __shfl_xor(sl, m, 64);
      sr += __shfl_xor(sr, m, 64);
    }
    if (f == 0) {
      el[row * HEADS + head] = sl;   // layout [n][4] -> float4 addressable
      er[row * HEADS + head] = sr;
    }
  }
}

template<int WITH_COUNT>
__global__ __launch_bounds__(256) void proj_kernel(
    const float* __restrict__ x, const float* __restrict__ W,
    const float* __restrict__ al, const float* __restrict__ ar,
    __half* __restrict__ h, float* __restrict__ el, float* __restrict__ er,
    const int* __restrict__ dst, int* __restrict__ deg) {
  if (WITH_COUNT && blockIdx.x >= PROJ_BLOCKS) {
    int e = (blockIdx.x - PROJ_BLOCKS) * 256 + threadIdx.x;
    if (e < EDGES) atomicAdd(&deg[dst[e]], 1);
    return;
  }
  proj_body(x, W, al, ar, h, el, er, blockIdx.x);
}

// ============ fused per-node: segment softmax + aggregation + bias/act/mean ====
__device__ __forceinline__ float lrelu(float s) { return s > 0.f ? s : NEG_SLOPE * s; }

__device__ __forceinline__ void gather_fma(const __half* __restrict__ h, int s,
                                           int hh, int fq, float av, float4& acc) {
  union { uint2 u; __half2 h2[2]; } cvt;
  cvt.u = *(const uint2*)(h + (size_t)s * HF + hh * FEAT + fq * 4);
  float2 f01 = __half22float2(cvt.h2[0]);
  float2 f23 = __half22float2(cvt.h2[1]);
  acc.x += f01.x * av;
  acc.y += f01.y * av;
  acc.z += f23.x * av;
  acc.w += f23.y * av;
}

template<int DO_TANH>
__global__ __launch_bounds__(256) void node_kernel(
    const int* __restrict__ rowstart, const int* __restrict__ deg,
    const int* __restrict__ csr_src,
    const float* __restrict__ el, const float* __restrict__ er,
    const __half* __restrict__ h, const float* __restrict__ bias,
    float* __restrict__ out) {
  const int node = (blockIdx.x * blockDim.x + threadIdx.x) >> 6;
  if (node >= NODES) return;
  const int lane = threadIdx.x & 63;
  const int hh = lane >> 4, fq = lane & 15;
  const int rs = rowstart[node];
  const int dg = deg[node];

  float4 acc = make_float4(0.f, 0.f, 0.f, 0.f);

  if (dg > 0) {
    const float4 erv = *(const float4*)&er[node * 4];
    if (dg <= 64) {
      // ---- fast path: one edge per lane; scores/alpha computed once ----
      int sL = 0;
      float s0 = -FLT_MAX, s1 = -FLT_MAX, s2 = -FLT_MAX, s3 = -FLT_MAX;
      if (lane < dg) {
        sL = csr_src[rs + lane];
        float4 ev = *(const float4*)&el[sL * 4];
        s0 = lrelu(ev.x + erv.x);
        s1 = lrelu(ev.y + erv.y);
        s2 = lrelu(ev.z + erv.z);
        s3 = lrelu(ev.w + erv.w);
      }
      float m0 = s0, m1 = s1, m2 = s2, m3 = s3;
#pragma unroll
      for (int off = 32; off; off >>= 1) {
        m0 = fmaxf(m0, __shfl_xor(m0, off, 64));
        m1 = fmaxf(m1, __shfl_xor(m1, off, 64));
        m2 = fmaxf(m2, __shfl_xor(m2, off, 64));
        m3 = fmaxf(m3, __shfl_xor(m3, off, 64));
      }
      float E0 = 0.f, E1 = 0.f, E2 = 0.f, E3 = 0.f;
      if (lane < dg) {
        E0 = __expf(s0 - m0);
        E1 = __expf(s1 - m1);
        E2 = __expf(s2 - m2);
        E3 = __expf(s3 - m3);
      }
      float q0 = E0, q1 = E1, q2 = E2, q3 = E3;
#pragma unroll
      for (int off = 32; off; off >>= 1) {
        q0 += __shfl_xor(q0, off, 64);
        q1 += __shfl_xor(q1, off, 64);
        q2 += __shfl_xor(q2, off, 64);
        q3 += __shfl_xor(q3, off, 64);
      }
      const float A0 = E0 / q0, A1 = E1 / q1, A2 = E2 / q2, A3 = E3 / q3;
      for (int i = 0; i < dg; ++i) {
        const int s = __shfl(sL, i, 64);
        const float a0 = __shfl(A0, i, 64);
        const float a1 = __shfl(A1, i, 64);
        const float a2 = __shfl(A2, i, 64);
        const float a3 = __shfl(A3, i, 64);
        const float av = (hh == 0) ? a0 : (hh == 1) ? a1 : (hh == 2) ? a2 : a3;
        gather_fma(h, s, hh, fq, av, acc);
      }
    } else {
      // ---- general 3-pass path (deg > 64; rare) ----
      float m0 = -FLT_MAX, m1 = -FLT_MAX, m2 = -FLT_MAX, m3 = -FLT_MAX;
      for (int i = lane; i < dg; i += 64) {
        int s = csr_src[rs + i];
        float4 ev = *(const float4*)&el[s * 4];
        m0 = fmaxf(m0, lrelu(ev.x + erv.x));
        m1 = fmaxf(m1, lrelu(ev.y + erv.y));
        m2 = fmaxf(m2, lrelu(ev.z + erv.z));
        m3 = fmaxf(m3, lrelu(ev.w + erv.w));
      }
#pragma unroll
      for (int off = 32; off; off >>= 1) {
        m0 = fmaxf(m0, __shfl_xor(m0, off, 64));
        m1 = fmaxf(m1, __shfl_xor(m1, off, 64));
        m2 = fmaxf(m2, __shfl_xor(m2, off, 64));
        m3 = fmaxf(m3, __shfl_xor(m3, off, 64));
      }
      float q0 = 0.f, q1 = 0.f, q2 = 0.f, q3 = 0.f;
      for (int i = lane; i < dg; i += 64) {
        int s = csr_src[rs + i];
        float4 ev = *(const float4*)&el[s * 4];
        q0 += __expf(lrelu(ev.x + erv.x) - m0);
        q1 += __expf(lrelu(ev.y + erv.y) - m1);
        q2 += __expf(lrelu(ev.z + erv.z) - m2);
        q3 += __expf(lrelu(ev.w + erv.w) - m3);
      }
#pragma unroll
      for (int off = 32; off; off >>= 1) {
        q0 += __shfl_xor(q0, off, 64);
        q1 += __shfl_xor(q1, off, 64);
        q2 += __shfl_xor(q2, off, 64);
        q3 += __shfl_xor(q3, off, 64);
      }
      const float r0 = 1.f / q0, r1 = 1.f / q1, r2 = 1.f / q2, r3 = 1.f / q3;
      for (int base = 0; base < dg; base += 64) {
        const int cnt = min(64, dg - base);
        int sL = 0;
        float A0 = 0.f, A1 = 0.f, A2 = 0.f, A3 = 0.f;
        if (base + lane < dg) {
          sL = csr_src[rs + base + lane];
          float4 ev = *(const float4*)&el[sL * 4];
          A0 = __expf(lrelu(ev.x + erv.x) - m0) * r0;
          A1 = __expf(lrelu(ev.y + erv.y) - m1) * r1;
          A2 = __expf(lrelu(ev.z + erv.z) - m2) * r2;
          A3 = __expf(lrelu(ev.w + erv.w) - m3) * r3;
        }
        for (int i = 0; i < cnt; ++i) {
          const int s = __shfl(sL, i, 64);
          const float a0 = __shfl(A0, i, 64);
          const float a1 = __shfl(A1, i, 64);
          const float a2 = __shfl(A2, i, 64);
          const float a3 = __shfl(A3, i, 64);
          const float av = (hh == 0) ? a0 : (hh == 1) ? a1 : (hh == 2) ? a2 : a3;
          gather_fma(h, s, hh, fq, av, acc);
        }
      }
    }
  }

  // ---- bias + activation + head-mean (cross-head shfl reduce) ----
  const float4 bv = *(const float4*)&bias[hh * FEAT + fq * 4];
  float vx = acc.x + bv.x, vy = acc.y + bv.y, vz = acc.z + bv.z, vw = acc.w + bv.w;
  if (DO_TANH) { vx = tanhf(vx); vy = tanhf(vy); vz = tanhf(vz); vw = tanhf(vw); }
#pragma unroll
  for (int off = 16; off <= 32; off <<= 1) {
    vx += __shfl_xor(vx, off, 64);
    vy += __shfl_xor(vy, off, 64);
    vz += __shfl_xor(vz, off, 64);
    vw += __shfl_xor(vw, off, 64);
  }
  if (hh == 0) {
    *(float4*)&out[(size_t)node * FEAT + fq * 4] =
        make_float4(vx * 0.25f, vy * 0.25f, vz * 0.25f, vw * 0.25f);
  }
}

// ============ launch ============

extern "C" void kernel_launch(void* const* d_in, const int* in_sizes, int n_in,
                              void* d_out, int out_size, void* d_ws, size_t ws_size,
                              hipStream_t stream) {
  const float* x   = (const float*)d_in[0];
  const int*   src = (const int*)d_in[1];
  const int*   dst = (const int*)d_in[2];
  const float* Ws[2]  = {(const float*)d_in[3], (const float*)d_in[7]};
  const float* als[2] = {(const float*)d_in[4], (const float*)d_in[8]};
  const float* ars[2] = {(const float*)d_in[5], (const float*)d_in[9]};
  const float* bs[2]  = {(const float*)d_in[6], (const float*)d_in[10]};

  float* ws = (float*)d_ws;
  const size_t NHF = (size_t)NODES * HF;   // 12.8M elems
  const size_t NF  = (size_t)NODES * FEAT; // 3.2M
  const size_t NH  = (size_t)NODES * HEADS;// 200K
  __half* hbuf = (__half*)ws;              // NHF halves = NHF/2 float slots
  float* x2   = ws + NHF / 2;
  float* el   = x2 + NF;
  float* er   = el + NH;
  int* ibase   = (int*)(er + NH);
  int* deg      = ibase;
  int* rowstart = ibase + NODES;
  int* cursor   = ibase + 2 * NODES;
  int* csr_src  = ibase + 3 * NODES;
  float* outp = (float*)d_out;

  const int edge_grid = (EDGES + 255) / 256;
  const int node_grid = (NODES * 64) / 256;  // one wave per node
  const int n_grid    = (NODES + 255) / 256;

  // zero degrees, then layer-1 projection fused with degree count
  zero_deg_kernel<<<n_grid, 256, 0, stream>>>(deg);
  proj_kernel<1><<<PROJ_BLOCKS + COUNT_BLOCKS, 256, 0, stream>>>(
      x, Ws[0], als[0], ars[0], hbuf, el, er, dst, deg);
  scan_kernel<<<1, 1024, 0, stream>>>(deg, rowstart, cursor);
  scatter_kernel<<<edge_grid, 256, 0, stream>>>(src, dst, cursor, csr_src);

  node_kernel<1><<<node_grid, 256, 0, stream>>>(rowstart, deg, csr_src, el, er,
                                                hbuf, bs[0], x2);
  proj_kernel<0><<<PROJ_BLOCKS, 256, 0, stream>>>(
      x2, Ws[1], als[1], ars[1], hbuf, el, er, dst, deg);
  node_kernel<0><<<node_grid, 256, 0, stream>>>(rowstart, deg, csr_src, el, er,
                                                hbuf, bs[1], outp);
}

// Round 15
// 460.817 us; speedup vs baseline: 12.4219x; 1.0077x over previous
//
#include <hip/hip_runtime.h>
#include <hip/hip_fp16.h>
#include <cfloat>
#include <cstddef>

#define NODES 50000
#define EDGES 800000
#define HEADS 4
#define FEAT  64
#define HF    256   // HEADS*FEAT
#define NEG_SLOPE 0.2f

#define ROWS 32
#define PROJ_BLOCKS ((NODES + ROWS - 1) / ROWS)   // 1563
#define COUNT_BLOCKS ((EDGES + 255) / 256)        // 3125

// ============ CSR build ============

__global__ void zero_deg_kernel(int* __restrict__ deg) {
  int i = blockIdx.x * blockDim.x + threadIdx.x;
  if (i < NODES) deg[i] = 0;
}

// LDS-staged single-block scan: 4 chunks of 13312, coalesced I/O, 13 elems/thread.
#define SCHUNK 13312
#define SPER   13
__global__ __launch_bounds__(1024) void scan_kernel(const int* __restrict__ deg,
                                                    int* __restrict__ rowstart,
                                                    int* __restrict__ cursor) {
  __shared__ int buf[SCHUNK];          // 52 KB
  __shared__ int wsum[16];
  __shared__ int carry_s;
  const int tid = threadIdx.x, lane = tid & 63, wv = tid >> 6;
  if (tid == 0) carry_s = 0;
  for (int base = 0; base < NODES; base += SCHUNK) {
    const int sz = min(SCHUNK, NODES - base);
    for (int i = tid; i < sz; i += 1024) buf[i] = deg[base + i];
    __syncthreads();
    const int o = tid * SPER;
    int tsum = 0;
#pragma unroll
    for (int j = 0; j < SPER; ++j) {
      int idx = o + j;
      if (idx < sz) tsum += buf[idx];
    }
    int x = tsum;
#pragma unroll
    for (int off = 1; off < 64; off <<= 1) {
      int u = __shfl_up(x, off, 64);
      if (lane >= off) x += u;
    }
    if (lane == 63) wsum[wv] = x;
    __syncthreads();
    if (wv == 0) {
      int wval = (lane < 16) ? wsum[lane] : 0;
      int wx = wval;
#pragma unroll
      for (int off = 1; off < 16; off <<= 1) {
        int u = __shfl_up(wx, off, 64);
        if (lane >= off) wx += u;
      }
      if (lane < 16) wsum[lane] = wx - wval;   // exclusive wave offsets
    }
    __syncthreads();
    const int carry = carry_s;
    int run = carry + wsum[wv] + (x - tsum);   // thread's exclusive prefix
#pragma unroll
    for (int j = 0; j < SPER; ++j) {
      int idx = o + j;
      if (idx < sz) { int t = buf[idx]; buf[idx] = run; run += t; }
    }
    __syncthreads();
    for (int i = tid; i < sz; i += 1024) {
      int v = buf[i];
      rowstart[base + i] = v;
      cursor[base + i] = v;
    }
    __syncthreads();
    if (tid == 1023) carry_s = run;            // = carry + chunk total
    __syncthreads();
  }
}

__global__ void scatter_kernel(const int* __restrict__ src, const int* __restrict__ dst,
                               int* __restrict__ cursor, int* __restrict__ csr_src) {
  int e = blockIdx.x * blockDim.x + threadIdx.x;
  if (e < EDGES) {
    int pos = atomicAdd(&cursor[dst[e]], 1);
    csr_src[pos] = src[e];
  }
}

// ============ fused projection GEMM + attention logits (+optional edge count) ====
// proj blocks: thread owns one output column (64 W regs); x rows in LDS.
// __launch_bounds__(256, 2): 2 waves/EU floor -> ~256 VGPR budget, keeps Wc[64]
// register-resident (round-8 profile showed VGPR_Count=56 => Wc spilled to scratch).
__device__ __forceinline__ void proj_body(
    const float* __restrict__ x, const float* __restrict__ W,
    const float* __restrict__ al, const float* __restrict__ ar,
    __half* __restrict__ h, float* __restrict__ el, float* __restrict__ er,
    int blk) {
  __shared__ float xs[ROWS * FEAT];
  const int c = threadIdx.x;          // output column 0..255
  const int head = c >> 6, f = c & 63;

  float Wc[FEAT];
#pragma unroll
  for (int k = 0; k < FEAT; ++k) Wc[k] = W[k * HF + c];
  const float alv = al[head * FEAT + f];
  const float arv = ar[head * FEAT + f];

  const int row0 = blk * ROWS;
  for (int i = c; i < ROWS * FEAT; i += 256) {
    int r = row0 + (i >> 6);
    xs[i] = (r < NODES) ? x[r * FEAT + (i & 63)] : 0.f;
  }
  __syncthreads();

  for (int r = 0; r < ROWS; ++r) {
    const int row = row0 + r;
    if (row >= NODES) break;
    const float4* xr = (const float4*)&xs[r * FEAT];
    float vs0 = 0.f, vs1 = 0.f, vs2 = 0.f, vs3 = 0.f;
#pragma unroll
    for (int k4 = 0; k4 < 16; k4 += 4) {
      float4 a = xr[k4 + 0];
      float4 b = xr[k4 + 1];
      float4 cc = xr[k4 + 2];
      float4 d = xr[k4 + 3];
      vs0 += a.x * Wc[4 * k4 + 0] + a.y * Wc[4 * k4 + 1] +
             a.z * Wc[4 * k4 + 2] + a.w * Wc[4 * k4 + 3];
      vs1 += b.x * Wc[4 * k4 + 4] + b.y * Wc[4 * k4 + 5] +
             b.z * Wc[4 * k4 + 6] + b.w * Wc[4 * k4 + 7];
      vs2 += cc.x * Wc[4 * k4 + 8] + cc.y * Wc[4 * k4 + 9] +
             cc.z * Wc[4 * k4 + 10] + cc.w * Wc[4 * k4 + 11];
      vs3 += d.x * Wc[4 * k4 + 12] + d.y * Wc[4 * k4 + 13] +
             d.z * Wc[4 * k4 + 14] + d.w * Wc[4 * k4 + 15];
    }
    const float v = (vs0 + vs1) + (vs2 + vs3);
    h[(size_t)row * HF + c] = __float2half(v);
    float sl = v * alv, sr = v * arv;
#pragma unroll
    for (int m = 32; m; m >>= 1) {
      sl += __shfl_xor(sl, m, 64);
      sr += __shfl_xor(sr, m, 64);
    }
    if (f == 0) {
      el[row * HEADS + head] = sl;   // layout [n][4] -> float4 addressable
      er[row * HEADS + head] = sr;
    }
  }
}

template<int WITH_COUNT>
__global__ __launch_bounds__(256, 2) void proj_kernel(
    const float* __restrict__ x, const float* __restrict__ W,
    const float* __restrict__ al, const float* __restrict__ ar,
    __half* __restrict__ h, float* __restrict__ el, float* __restrict__ er,
    const int* __restrict__ dst, int* __restrict__ deg) {
  if (WITH_COUNT && blockIdx.x >= PROJ_BLOCKS) {
    int e = (blockIdx.x - PROJ_BLOCKS) * 256 + threadIdx.x;
    if (e < EDGES) atomicAdd(&deg[dst[e]], 1);
    return;
  }
  proj_body(x, W, al, ar, h, el, er, blockIdx.x);
}

// ============ fused per-node: segment softmax + aggregation + bias/act/mean ====
__device__ __forceinline__ float lrelu(float s) { return s > 0.f ? s : NEG_SLOPE * s; }

__device__ __forceinline__ void gather_fma(const __half* __restrict__ h, int s,
                                           int hh, int fq, float av, float4& acc) {
  union { uint2 u; __half2 h2[2]; } cvt;
  cvt.u = *(const uint2*)(h + (size_t)s * HF + hh * FEAT + fq * 4);
  float2 f01 = __half22float2(cvt.h2[0]);
  float2 f23 = __half22float2(cvt.h2[1]);
  acc.x += f01.x * av;
  acc.y += f01.y * av;
  acc.z += f23.x * av;
  acc.w += f23.y * av;
}

template<int DO_TANH>
__global__ __launch_bounds__(256) void node_kernel(
    const int* __restrict__ rowstart, const int* __restrict__ deg,
    const int* __restrict__ csr_src,
    const float* __restrict__ el, const float* __restrict__ er,
    const __half* __restrict__ h, const float* __restrict__ bias,
    float* __restrict__ out) {
  const int node = (blockIdx.x * blockDim.x + threadIdx.x) >> 6;
  if (node >= NODES) return;
  const int lane = threadIdx.x & 63;
  const int hh = lane >> 4, fq = lane & 15;
  const int rs = rowstart[node];
  const int dg = deg[node];

  float4 acc = make_float4(0.f, 0.f, 0.f, 0.f);

  if (dg > 0) {
    const float4 erv = *(const float4*)&er[node * 4];
    if (dg <= 64) {
      // ---- fast path: one edge per lane; scores/alpha computed once ----
      int sL = 0;
      float s0 = -FLT_MAX, s1 = -FLT_MAX, s2 = -FLT_MAX, s3 = -FLT_MAX;
      if (lane < dg) {
        sL = csr_src[rs + lane];
        float4 ev = *(const float4*)&el[sL * 4];
        s0 = lrelu(ev.x + erv.x);
        s1 = lrelu(ev.y + erv.y);
        s2 = lrelu(ev.z + erv.z);
        s3 = lrelu(ev.w + erv.w);
      }
      float m0 = s0, m1 = s1, m2 = s2, m3 = s3;
#pragma unroll
      for (int off = 32; off; off >>= 1) {
        m0 = fmaxf(m0, __shfl_xor(m0, off, 64));
        m1 = fmaxf(m1, __shfl_xor(m1, off, 64));
        m2 = fmaxf(m2, __shfl_xor(m2, off, 64));
        m3 = fmaxf(m3, __shfl_xor(m3, off, 64));
      }
      float E0 = 0.f, E1 = 0.f, E2 = 0.f, E3 = 0.f;
      if (lane < dg) {
        E0 = __expf(s0 - m0);
        E1 = __expf(s1 - m1);
        E2 = __expf(s2 - m2);
        E3 = __expf(s3 - m3);
      }
      float q0 = E0, q1 = E1, q2 = E2, q3 = E3;
#pragma unroll
      for (int off = 32; off; off >>= 1) {
        q0 += __shfl_xor(q0, off, 64);
        q1 += __shfl_xor(q1, off, 64);
        q2 += __shfl_xor(q2, off, 64);
        q3 += __shfl_xor(q3, off, 64);
      }
      const float A0 = E0 / q0, A1 = E1 / q1, A2 = E2 / q2, A3 = E3 / q3;
      for (int i = 0; i < dg; ++i) {
        const int s = __shfl(sL, i, 64);
        const float a0 = __shfl(A0, i, 64);
        const float a1 = __shfl(A1, i, 64);
        const float a2 = __shfl(A2, i, 64);
        const float a3 = __shfl(A3, i, 64);
        const float av = (hh == 0) ? a0 : (hh == 1) ? a1 : (hh == 2) ? a2 : a3;
        gather_fma(h, s, hh, fq, av, acc);
      }
    } else {
      // ---- general 3-pass path (deg > 64; rare) ----
      float m0 = -FLT_MAX, m1 = -FLT_MAX, m2 = -FLT_MAX, m3 = -FLT_MAX;
      for (int i = lane; i < dg; i += 64) {
        int s = csr_src[rs + i];
        float4 ev = *(const float4*)&el[s * 4];
        m0 = fmaxf(m0, lrelu(ev.x + erv.x));
        m1 = fmaxf(m1, lrelu(ev.y + erv.y));
        m2 = fmaxf(m2, lrelu(ev.z + erv.z));
        m3 = fmaxf(m3, lrelu(ev.w + erv.w));
      }
#pragma unroll
      for (int off = 32; off; off >>= 1) {
        m0 = fmaxf(m0, __shfl_xor(m0, off, 64));
        m1 = fmaxf(m1, __shfl_xor(m1, off, 64));
        m2 = fmaxf(m2, __shfl_xor(m2, off, 64));
        m3 = fmaxf(m3, __shfl_xor(m3, off, 64));
      }
      float q0 = 0.f, q1 = 0.f, q2 = 0.f, q3 = 0.f;
      for (int i = lane; i < dg; i += 64) {
        int s = csr_src[rs + i];
        float4 ev = *(const float4*)&el[s * 4];
        q0 += __expf(lrelu(ev.x + erv.x) - m0);
        q1 += __expf(lrelu(ev.y + erv.y) - m1);
        q2 += __expf(lrelu(ev.z + erv.z) - m2);
        q3 += __expf(lrelu(ev.w + erv.w) - m3);
      }
#pragma unroll
      for (int off = 32; off; off >>= 1) {
        q0 += __shfl_xor(q0, off, 64);
        q1 += __shfl_xor(q1, off, 64);
        q2 += __shfl_xor(q2, off, 64);
        q3 += __shfl_xor(q3, off, 64);
      }
      const float r0 = 1.f / q0, r1 = 1.f / q1, r2 = 1.f / q2, r3 = 1.f / q3;
      for (int base = 0; base < dg; base += 64) {
        const int cnt = min(64, dg - base);
        int sL = 0;
        float A0 = 0.f, A1 = 0.f, A2 = 0.f, A3 = 0.f;
        if (base + lane < dg) {
          sL = csr_src[rs + base + lane];
          float4 ev = *(const float4*)&el[sL * 4];
          A0 = __expf(lrelu(ev.x + erv.x) - m0) * r0;
          A1 = __expf(lrelu(ev.y + erv.y) - m1) * r1;
          A2 = __expf(lrelu(ev.z + erv.z) - m2) * r2;
          A3 = __expf(lrelu(ev.w + erv.w) - m3) * r3;
        }
        for (int i = 0; i < cnt; ++i) {
          const int s = __shfl(sL, i, 64);
          const float a0 = __shfl(A0, i, 64);
          const float a1 = __shfl(A1, i, 64);
          const float a2 = __shfl(A2, i, 64);
          const float a3 = __shfl(A3, i, 64);
          const float av = (hh == 0) ? a0 : (hh == 1) ? a1 : (hh == 2) ? a2 : a3;
          gather_fma(h, s, hh, fq, av, acc);
        }
      }
    }
  }

  // ---- bias + activation + head-mean (cross-head shfl reduce) ----
  const float4 bv = *(const float4*)&bias[hh * FEAT + fq * 4];
  float vx = acc.x + bv.x, vy = acc.y + bv.y, vz = acc.z + bv.z, vw = acc.w + bv.w;
  if (DO_TANH) { vx = tanhf(vx); vy = tanhf(vy); vz = tanhf(vz); vw = tanhf(vw); }
#pragma unroll
  for (int off = 16; off <= 32; off <<= 1) {
    vx += __shfl_xor(vx, off, 64);
    vy += __shfl_xor(vy, off, 64);
    vz += __shfl_xor(vz, off, 64);
    vw += __shfl_xor(vw, off, 64);
  }
  if (hh == 0) {
    *(float4*)&out[(size_t)node * FEAT + fq * 4] =
        make_float4(vx * 0.25f, vy * 0.25f, vz * 0.25f, vw * 0.25f);
  }
}

// ============ launch ============

extern "C" void kernel_launch(void* const* d_in, const int* in_sizes, int n_in,
                              void* d_out, int out_size, void* d_ws, size_t ws_size,
                              hipStream_t stream) {
  const float* x   = (const float*)d_in[0];
  const int*   src = (const int*)d_in[1];
  const int*   dst = (const int*)d_in[2];
  const float* Ws[2]  = {(const float*)d_in[3], (const float*)d_in[7]};
  const float* als[2] = {(const float*)d_in[4], (const float*)d_in[8]};
  const float* ars[2] = {(const float*)d_in[5], (const float*)d_in[9]};
  const float* bs[2]  = {(const float*)d_in[6], (const float*)d_in[10]};

  float* ws = (float*)d_ws;
  const size_t NHF = (size_t)NODES * HF;   // 12.8M elems
  const size_t NF  = (size_t)NODES * FEAT; // 3.2M
  const size_t NH  = (size_t)NODES * HEADS;// 200K
  __half* hbuf = (__half*)ws;              // NHF halves = NHF/2 float slots
  float* x2   = ws + NHF / 2;
  float* el   = x2 + NF;
  float* er   = el + NH;
  int* ibase   = (int*)(er + NH);
  int* deg      = ibase;
  int* rowstart = ibase + NODES;
  int* cursor   = ibase + 2 * NODES;
  int* csr_src  = ibase + 3 * NODES;
  float* outp = (float*)d_out;

  const int edge_grid = (EDGES + 255) / 256;
  const int node_grid = (NODES * 64) / 256;  // one wave per node
  const int n_grid    = (NODES + 255) / 256;

  // zero degrees, then layer-1 projection fused with degree count
  zero_deg_kernel<<<n_grid, 256, 0, stream>>>(deg);
  proj_kernel<1><<<PROJ_BLOCKS + COUNT_BLOCKS, 256, 0, stream>>>(
      x, Ws[0], als[0], ars[0], hbuf, el, er, dst, deg);
  scan_kernel<<<1, 1024, 0, stream>>>(deg, rowstart, cursor);
  scatter_kernel<<<edge_grid, 256, 0, stream>>>(src, dst, cursor, csr_src);

  node_kernel<1><<<node_grid, 256, 0, stream>>>(rowstart, deg, csr_src, el, er,
                                                hbuf, bs[0], x2);
  proj_kernel<0><<<PROJ_BLOCKS, 256, 0, stream>>>(
      x2, Ws[1], als[1], ars[1], hbuf, el, er, dst, deg);
  node_kernel<0><<<node_grid, 256, 0, stream>>>(rowstart, deg, csr_src, el, er,
                                                hbuf, bs[1], outp);
}